// Round 14
// baseline (3365.245 us; speedup 1.0000x reference)
//
#include <hip/hip_runtime.h>
#include <hip/hip_bf16.h>
#include <hip/hip_fp16.h>

// ---------------------------------------------------------------------------
// Encoder: mean = APPNP(normalize(x@lin_w+b)*1.8), logstd = attention-pooled
// graph-wavelet branch.
// Round 14: r13 (2929us, validated) with steady slot mix rebalanced
// 8G/6B/2H -> 10G/4B/2H (gather is the likely pole and slot-scales; build is
// latency-bound and weakly slot-dependent). Constants-only change.
// ---------------------------------------------------------------------------

#define WS_HIST  2
#define WS_BUILD 4
#define WS_GATH  10  // of 16 slots per blockIdx group (steady state)

// ---------- standalone histogram (int atomics) ----------
__global__ __launch_bounds__(256) void hist_kernel(const int* __restrict__ idx,
                                                   int* __restrict__ cnt, int n) {
    int i = blockIdx.x * 256 + threadIdx.x;
    if (i < n) atomicAdd(&cnt[__builtin_nontemporal_load(idx + i)], 1);
}

// dinv from degree; zeroes cnt for the next histogram
__global__ __launch_bounds__(256) void dinv_kernel(int* __restrict__ cnt,
                                                   float* __restrict__ dinv, int n) {
    int i = blockIdx.x * 256 + threadIdx.x;
    if (i < n) { dinv[i] = rsqrtf((float)(cnt[i] + 1)); cnt[i] = 0; }
}

// ---------- 3-kernel exclusive scan of cnt[N] -> ptr[N+1] (chunks of 1024) --
__global__ __launch_bounds__(256) void scan_reduce_kernel(
    const int* __restrict__ cnt, int* __restrict__ bsum, int N) {
    __shared__ int wsum[4];
    int base = blockIdx.x * 1024;
    int t = threadIdx.x;
    int s = 0;
#pragma unroll
    for (int j = 0; j < 4; ++j) {
        int idx = base + t * 4 + j;
        if (idx < N) s += cnt[idx];
    }
#pragma unroll
    for (int off = 32; off; off >>= 1) s += __shfl_xor(s, off);
    int lane = t & 63, w = t >> 6;
    if (lane == 0) wsum[w] = s;
    __syncthreads();
    if (t == 0) bsum[blockIdx.x] = wsum[0] + wsum[1] + wsum[2] + wsum[3];
}

// serial scan of block sums (nblk ~98). bsum and bofs MUST be distinct.
__global__ void scan_bsum_kernel(const int* __restrict__ bsum,
                                 int* __restrict__ bofs,
                                 int* __restrict__ ptr, int nblk, int N) {
    if (threadIdx.x == 0 && blockIdx.x == 0) {
        int run = 0;
        for (int i = 0; i < nblk; ++i) { bofs[i] = run; run += bsum[i]; }
        bofs[nblk] = run;
        ptr[N] = run;
    }
}

// writes ptr/cursor AND zeroes cnt for the next histogram
__global__ __launch_bounds__(256) void scan_block_kernel(
    int* __restrict__ cnt, const int* __restrict__ bofs,
    int* __restrict__ ptr, int* __restrict__ cursor, int N) {
    __shared__ int wsum[4];
    int base = blockIdx.x * 1024;
    int t = threadIdx.x, lane = t & 63, w = t >> 6;
    int v[4]; int s = 0;
#pragma unroll
    for (int j = 0; j < 4; ++j) {
        int idx = base + t * 4 + j;
        v[j] = (idx < N) ? cnt[idx] : 0;
        s += v[j];
    }
    int incl = s;
#pragma unroll
    for (int off = 1; off < 64; off <<= 1) {
        int nn = __shfl_up(incl, off);
        if (lane >= off) incl += nn;
    }
    if (lane == 63) wsum[w] = incl;
    __syncthreads();
    int wofs = 0;
    for (int i = 0; i < w; ++i) wofs += wsum[i];
    int run = bofs[blockIdx.x] + wofs + incl - s;
#pragma unroll
    for (int j = 0; j < 4; ++j) {
        int idx = base + t * 4 + j;
        if (idx < N) { ptr[idx] = run; cursor[idx] = run; cnt[idx] = 0; }
        run += v[j];
    }
}

// ---------- fused pipeline kernel: gather(k) || build(k+1) || hist(k+2) -----
// build modes: 0: v=vals[e]; 1: v=vals[e]*diag[c]; 2: v=dinv[r]*dinv[c]
// cpair u64: hi32 = val bits, lo32 = col  (int2: x=col, y=val)
// mix: 0 = all-gather, 1 = steady 10G/4B/2H, 2 = prologue 12B/4H
__global__ __launch_bounds__(256) void fused_pipe_kernel(
    // gather role
    const int* __restrict__ ptr_g, const int2* __restrict__ cpair_g,
    const __half* __restrict__ src, const float* __restrict__ init_src,
    const float* __restrict__ dinv,
    float* __restrict__ dstf, __half* __restrict__ dsth, int N, int nnz_g,
    // build role
    const int* __restrict__ rows_b, const int* __restrict__ cols_b,
    const float* __restrict__ vals_b, const float* __restrict__ diag,
    int* __restrict__ cursor_b, unsigned long long* __restrict__ cpair_b,
    int nnz_b, int mode,
    // hist role
    const int* __restrict__ rows_h, int* __restrict__ cnt, int nnz_h,
    int mix)
{
    int role, lid, nloc;
    if (mix == 0) { role = 2; lid = blockIdx.x; nloc = gridDim.x; }
    else if (mix == 2) {
        int r = blockIdx.x & 15, g = blockIdx.x >> 4, ng = gridDim.x >> 4;
        if (r < 12) { role = 1; lid = g * 12 + r;        nloc = ng * 12; }
        else        { role = 0; lid = g * 4 + (r - 12);  nloc = ng * 4; }
    } else {
        int r = blockIdx.x & 15, g = blockIdx.x >> 4, ng = gridDim.x >> 4;
        if (r < WS_HIST)                { role = 0; lid = g * WS_HIST + r;                nloc = ng * WS_HIST; }
        else if (r < WS_HIST + WS_BUILD){ role = 1; lid = g * WS_BUILD + (r - WS_HIST);   nloc = ng * WS_BUILD; }
        else                            { role = 2; lid = g * WS_GATH + (r - WS_HIST - WS_BUILD); nloc = ng * WS_GATH; }
    }

    if (role == 0) {                       // ---- histogram (op k+2) ----
        if (!rows_h) return;
        int stride = nloc * 256;
        for (int i = lid * 256 + threadIdx.x; i < nnz_h; i += stride)
            atomicAdd(&cnt[__builtin_nontemporal_load(rows_h + i)], 1);
        return;
    }
    if (role == 1) {                       // ---- CSR build (op k+1) ----
        if (!rows_b) return;
        int stride = nloc * 256;
        for (int i = lid * 256 + threadIdx.x; i < nnz_b; i += stride) {
            int r = __builtin_nontemporal_load(rows_b + i);
            int c = __builtin_nontemporal_load(cols_b + i);
            float v;
            if (mode == 2) v = dinv[r] * dinv[c];
            else {
                v = __builtin_nontemporal_load(vals_b + i);
                if (mode == 1) v *= diag[c];
            }
            int pos = atomicAdd(&cursor_b[r], 1);
            unsigned long long pk =
                ((unsigned long long)(unsigned)__float_as_uint(v) << 32) | (unsigned)c;
            __builtin_nontemporal_store(pk, cpair_b + pos);
        }
        return;
    }

    // ---- gather (op k): wave per row, 16-deep load pipeline ----
    if (!ptr_g) return;
    const int lane = threadIdx.x & 63;
    const size_t lofs = (size_t)(lane * 2);
    int wid = (lid * 256 + threadIdx.x) >> 6;
    const int nwaves = (nloc * 256) >> 6;
    for (int row = wid; row < N; row += nwaves) {
        int s = ptr_g[row], e = ptr_g[row + 1];
        e = min(e, nnz_g); s = max(0, min(s, e));   // bad CSR must not fault
        float accx = 0.f, accy = 0.f;
        if (init_src) {
            float d = dinv[row];
            float dd = d * d;
            float2 m = *(const float2*)(init_src + (size_t)row * 128 + lofs);
            accx = dd * m.x; accy = dd * m.y;
        }
        for (int base = s; base < e; base += 64) {
            int n = min(64, e - base);
            int2 p = make_int2(0, 0);
            if (lane < n) p = cpair_g[base + lane];
            int j = 0;
            for (; j + 16 <= n; j += 16) {
                __half2 sv[16];
                float vj[16];
#pragma unroll
                for (int u = 0; u < 16; ++u) {
                    int cj = __builtin_amdgcn_readlane(p.x, j + u);
                    vj[u] = __int_as_float(__builtin_amdgcn_readlane(p.y, j + u));
                    sv[u] = *(const __half2*)(src + (size_t)cj * 128 + lofs);
                }
#pragma unroll
                for (int u = 0; u < 16; ++u) {
                    accx += vj[u] * __low2float(sv[u]);
                    accy += vj[u] * __high2float(sv[u]);
                }
            }
            for (; j + 4 <= n; j += 4) {
                __half2 sv[4];
                float vj[4];
#pragma unroll
                for (int u = 0; u < 4; ++u) {
                    int cj = __builtin_amdgcn_readlane(p.x, j + u);
                    vj[u] = __int_as_float(__builtin_amdgcn_readlane(p.y, j + u));
                    sv[u] = *(const __half2*)(src + (size_t)cj * 128 + lofs);
                }
#pragma unroll
                for (int u = 0; u < 4; ++u) {
                    accx += vj[u] * __low2float(sv[u]);
                    accy += vj[u] * __high2float(sv[u]);
                }
            }
            for (; j < n; ++j) {
                int cj = __builtin_amdgcn_readlane(p.x, j);
                float vj = __int_as_float(__builtin_amdgcn_readlane(p.y, j));
                __half2 sv = *(const __half2*)(src + (size_t)cj * 128 + lofs);
                accx += vj * __low2float(sv);
                accy += vj * __high2float(sv);
            }
        }
        if (dstf) {
            float2 o; o.x = accx; o.y = accy;
            *(float2*)(dstf + (size_t)row * 128 + lofs) = o;
        }
        if (dsth) {
            *(__half2*)(dsth + (size_t)row * 128 + lofs) =
                __floats2half2_rn(accx, accy);
        }
    }
}

// ---------- fused dual GEMM: mean0(fp32) = x@lin_w + b, xw(fp16) = x@gw_w ---
__global__ __launch_bounds__(256) void gemm_fused(
    const float* __restrict__ x, const float* __restrict__ lin_w,
    const float* __restrict__ lin_b, const float* __restrict__ gw_w,
    float* __restrict__ mean0, __half* __restrict__ xwh, int M) {
    __shared__ float As[32][68];
    __shared__ float Bs[32][64];
    const int tid = threadIdx.x;
    const int tx = tid & 15, ty = tid >> 4;
    const int row0 = blockIdx.x * 64;
    const int nt = blockIdx.y;
    const float* __restrict__ W = (nt < 2) ? lin_w : gw_w;
    const int colbase = (nt & 1) * 64;

    const int ar = tid >> 3;
    const int ac = (tid & 7) << 2;
    const int bk = tid >> 4;
    const int bn = (tid & 15) << 2;

    float acc[4][4] = {};

    for (int kt = 0; kt < 256; kt += 32) {
#pragma unroll
        for (int rr = 0; rr < 2; ++rr) {
            int r = ar + rr * 32;
            int grow = row0 + r;
            float4 v = make_float4(0.f, 0.f, 0.f, 0.f);
            if (grow < M) v = *(const float4*)(x + (size_t)grow * 256 + kt + ac);
            As[ac + 0][r] = v.x; As[ac + 1][r] = v.y;
            As[ac + 2][r] = v.z; As[ac + 3][r] = v.w;
        }
#pragma unroll
        for (int rr = 0; rr < 2; ++rr) {
            int k = bk + rr * 16;
            *(float4*)&Bs[k][bn] =
                *(const float4*)(W + (size_t)(kt + k) * 128 + colbase + bn);
        }
        __syncthreads();
#pragma unroll
        for (int k = 0; k < 32; ++k) {
            float4 a = *(const float4*)&As[k][ty * 4];
            float4 b = *(const float4*)&Bs[k][tx * 4];
            float av[4] = {a.x, a.y, a.z, a.w};
            float bv[4] = {b.x, b.y, b.z, b.w};
#pragma unroll
            for (int i = 0; i < 4; ++i)
#pragma unroll
                for (int j = 0; j < 4; ++j) acc[i][j] += av[i] * bv[j];
        }
        __syncthreads();
    }

    if (nt < 2) {
        float4 bb = *(const float4*)(lin_b + colbase + tx * 4);
#pragma unroll
        for (int i = 0; i < 4; ++i) {
            int grow = row0 + ty * 4 + i;
            if (grow < M) {
                float4 o = make_float4(acc[i][0] + bb.x, acc[i][1] + bb.y,
                                       acc[i][2] + bb.z, acc[i][3] + bb.w);
                *(float4*)(mean0 + (size_t)grow * 128 + colbase + tx * 4) = o;
            }
        }
    } else {
#pragma unroll
        for (int i = 0; i < 4; ++i) {
            int grow = row0 + ty * 4 + i;
            if (grow < M) {
                union { __half2 h[2]; int2 i2; } u;
                u.h[0] = __floats2half2_rn(acc[i][0], acc[i][1]);
                u.h[1] = __floats2half2_rn(acc[i][2], acc[i][3]);
                *(int2*)(xwh + (size_t)grow * 128 + colbase + tx * 4) = u.i2;
            }
        }
    }
}

// ---------- row L2-normalize * 1.8 in place + fp16 copy (wave per row) -----
__global__ __launch_bounds__(256) void rownorm_kernel(float* __restrict__ m,
                                                      __half* __restrict__ mh,
                                                      int n) {
    const int lane = threadIdx.x & 63;
    int wid = (blockIdx.x * 256 + threadIdx.x) >> 6;
    if (wid >= n) return;
    float2 v = *(float2*)(m + (size_t)wid * 128 + lane * 2);
    float ss = v.x * v.x + v.y * v.y;
#pragma unroll
    for (int off = 32; off; off >>= 1) ss += __shfl_xor(ss, off);
    float s = sqrtf(ss);
    float sc = 1.8f / fmaxf(s, 1e-12f);
    v.x *= sc; v.y *= sc;
    *(float2*)(m + (size_t)wid * 128 + lane * 2) = v;
    *(__half2*)(mh + (size_t)wid * 128 + lane * 2) = __floats2half2_rn(v.x, v.y);
}

// ---------- attention pool, fp16 z0/z1 + fp32 z2, in-place on z2 ----------
__global__ __launch_bounds__(256) void attn_h_kernel(
    const __half* __restrict__ z0, const __half* __restrict__ z1,
    const float* __restrict__ z2, const float* __restrict__ w1,
    const float* __restrict__ b1, const float* __restrict__ w2,
    float* __restrict__ out, int n) {
    const int lane = threadIdx.x & 63;
    float w1reg[128];
#pragma unroll
    for (int d = 0; d < 128; ++d) w1reg[d] = w1[d * 64 + lane];
    const float b1l = b1[lane];
    const float w2l = w2[lane];

    int wid = (blockIdx.x * 256 + threadIdx.x) >> 6;
    const int nwaves = (gridDim.x * 256) >> 6;
    for (int node = wid; node < n; node += nwaves) {
        float2 za = __half22float2(*(const __half2*)(z0 + (size_t)node * 128 + lane * 2));
        float2 zb = __half22float2(*(const __half2*)(z1 + (size_t)node * 128 + lane * 2));
        float2 zc = *(const float2*)(z2 + (size_t)node * 128 + lane * 2);
        float wk[3];
#pragma unroll
        for (int k = 0; k < 3; ++k) {
            float zx = (k == 0) ? za.x : (k == 1) ? zb.x : zc.x;
            float zy = (k == 0) ? za.y : (k == 1) ? zb.y : zc.y;
            float acc = 0.f;
#pragma unroll
            for (int d2 = 0; d2 < 64; ++d2) {
                float ze = __uint_as_float(__builtin_amdgcn_readlane(__float_as_uint(zx), d2));
                float zo = __uint_as_float(__builtin_amdgcn_readlane(__float_as_uint(zy), d2));
                acc += ze * w1reg[2 * d2] + zo * w1reg[2 * d2 + 1];
            }
            float h = fmaxf(acc + b1l, 0.f) * w2l;
#pragma unroll
            for (int off = 32; off; off >>= 1) h += __shfl_xor(h, off);
            wk[k] = h;
        }
        float mx = fmaxf(wk[0], fmaxf(wk[1], wk[2]));
        float e0 = __expf(wk[0] - mx);
        float e1 = __expf(wk[1] - mx);
        float e2 = __expf(wk[2] - mx);
        float inv = 1.f / (e0 + e1 + e2);
        float be0 = e0 * inv, be1 = e1 * inv, be2 = e2 * inv;
        float2 o;
        o.x = be0 * za.x + be1 * zb.x + be2 * zc.x;
        o.y = be0 * za.y + be1 * zb.y + be2 * zc.y;
        *(float2*)(out + (size_t)node * 128 + lane * 2) = o;
    }
}

// ---------- fallback-only kernels (atomic scatter path, fp32 z) ----------
__global__ __launch_bounds__(256) void f2h_kernel(const float* __restrict__ in,
                                                  __half* __restrict__ out,
                                                  size_t n2) {
    size_t i = (size_t)blockIdx.x * 256 + threadIdx.x;
    if (i >= n2) return;
    float2 v = ((const float2*)in)[i];
    ((__half2*)out)[i] = __floats2half2_rn(v.x, v.y);
}

__global__ __launch_bounds__(256) void spmm_h_kernel(
    const int* __restrict__ rows, const int* __restrict__ cols,
    const float* __restrict__ vals, const float* __restrict__ diag,
    const __half* __restrict__ src, float* __restrict__ dst, int nnz) {
    const int lane = threadIdx.x & 63;
    int wid = (blockIdx.x * 256 + threadIdx.x) >> 6;
    const int nwaves = (gridDim.x * 256) >> 6;
    for (int e = wid; e < nnz; e += nwaves) {
        int r = rows[e];
        int c = cols[e];
        float v = vals ? vals[e] : 1.f;
        if (diag) v *= diag[c];
        __half2 sh = *(const __half2*)(src + (size_t)c * 128 + lane * 2);
        float* d = dst + (size_t)r * 128 + lane * 2;
        unsafeAtomicAdd(d,     v * __low2float(sh));
        unsafeAtomicAdd(d + 1, v * __high2float(sh));
    }
}

__global__ __launch_bounds__(256) void appnp_init_kernel(
    const float* __restrict__ mean0, const float* __restrict__ dinv,
    float* __restrict__ dst, int n) {
    int i = blockIdx.x * 256 + threadIdx.x;
    if (i >= n * 32) return;
    int node = i >> 5;
    float dv = dinv[node];
    float dd = dv * dv;
    float4 v = ((const float4*)mean0)[i];
    v.x *= dd; v.y *= dd; v.z *= dd; v.w *= dd;
    ((float4*)dst)[i] = v;
}

__global__ __launch_bounds__(256) void appnp_edge_h_kernel(
    const int* __restrict__ rows, const int* __restrict__ cols,
    const float* __restrict__ dinv, const __half* __restrict__ src,
    float* __restrict__ dst, int nnz) {
    const int lane = threadIdx.x & 63;
    int wid = (blockIdx.x * 256 + threadIdx.x) >> 6;
    const int nwaves = (gridDim.x * 256) >> 6;
    for (int e = wid; e < nnz; e += nwaves) {
        int r = rows[e];
        int c = cols[e];
        float v = dinv[r] * dinv[c];
        __half2 sh = *(const __half2*)(src + (size_t)c * 128 + lane * 2);
        float* d = dst + (size_t)r * 128 + lane * 2;
        unsafeAtomicAdd(d,     v * __low2float(sh));
        unsafeAtomicAdd(d + 1, v * __high2float(sh));
    }
}

__global__ __launch_bounds__(256) void attn_f_kernel(
    const float* __restrict__ z0, const float* __restrict__ z1,
    const float* __restrict__ z2, const float* __restrict__ w1,
    const float* __restrict__ b1, const float* __restrict__ w2,
    float* __restrict__ out, int n) {
    const int lane = threadIdx.x & 63;
    float w1reg[128];
#pragma unroll
    for (int d = 0; d < 128; ++d) w1reg[d] = w1[d * 64 + lane];
    const float b1l = b1[lane];
    const float w2l = w2[lane];
    int wid = (blockIdx.x * 256 + threadIdx.x) >> 6;
    const int nwaves = (gridDim.x * 256) >> 6;
    for (int node = wid; node < n; node += nwaves) {
        float2 za = *(const float2*)(z0 + (size_t)node * 128 + lane * 2);
        float2 zb = *(const float2*)(z1 + (size_t)node * 128 + lane * 2);
        float2 zc = *(const float2*)(z2 + (size_t)node * 128 + lane * 2);
        float wk[3];
#pragma unroll
        for (int k = 0; k < 3; ++k) {
            float zx = (k == 0) ? za.x : (k == 1) ? zb.x : zc.x;
            float zy = (k == 0) ? za.y : (k == 1) ? zb.y : zc.y;
            float acc = 0.f;
#pragma unroll
            for (int d2 = 0; d2 < 64; ++d2) {
                float ze = __uint_as_float(__builtin_amdgcn_readlane(__float_as_uint(zx), d2));
                float zo = __uint_as_float(__builtin_amdgcn_readlane(__float_as_uint(zy), d2));
                acc += ze * w1reg[2 * d2] + zo * w1reg[2 * d2 + 1];
            }
            float h = fmaxf(acc + b1l, 0.f) * w2l;
#pragma unroll
            for (int off = 32; off; off >>= 1) h += __shfl_xor(h, off);
            wk[k] = h;
        }
        float mx = fmaxf(wk[0], fmaxf(wk[1], wk[2]));
        float e0 = __expf(wk[0] - mx);
        float e1 = __expf(wk[1] - mx);
        float e2 = __expf(wk[2] - mx);
        float inv = 1.f / (e0 + e1 + e2);
        float be0 = e0 * inv, be1 = e1 * inv, be2 = e2 * inv;
        float2 o;
        o.x = be0 * za.x + be1 * zb.x + be2 * zc.x;
        o.y = be0 * za.y + be1 * zb.y + be2 * zc.y;
        *(float2*)(out + (size_t)node * 128 + lane * 2) = o;
    }
}

// ---------------------------------------------------------------------------
extern "C" void kernel_launch(void* const* d_in, const int* in_sizes, int n_in,
                              void* d_out, int out_size, void* d_ws, size_t ws_size,
                              hipStream_t stream)
{
    const float* x            = (const float*)d_in[0];
    const int*   edge_index   = (const int*)d_in[1];    // [2,E]
    const int*   phi_idx      = (const int*)d_in[2];    // [K,2,NNZ]
    const float* phi_vals     = (const float*)d_in[3];  // [K,NNZ]
    const int*   phi_inv_idx  = (const int*)d_in[4];
    const float* phi_inv_vals = (const float*)d_in[5];
    const float* lin_w        = (const float*)d_in[6];
    const float* lin_b        = (const float*)d_in[7];
    const float* gw_w         = (const float*)d_in[8];
    const float* diag_w       = (const float*)d_in[9];
    const float* att_w1       = (const float*)d_in[10];
    const float* att_b1       = (const float*)d_in[11];
    const float* att_w2       = (const float*)d_in[12];

    const int N   = in_sizes[9];
    const int E   = in_sizes[1] / 2;
    const int NNZ = in_sizes[3] / 3;
    const size_t NF = (size_t)N * 128;
    const int MAXNNZ = (E > NNZ) ? E : NNZ;
    const int nblk = (N + 1023) / 1024;

    float* out0 = (float*)d_out;          // final: mean
    float* out1 = out0 + NF;              // final: logstd (temp: mean0, then z2)

    // ---- workspace layout ----
    char* p = (char*)d_ws;
    int*    cnt   = (int*)p;       p += (size_t)N * 4;
    float*  dinv  = (float*)p;     p += (size_t)N * 4;
    __half* xwh   = (__half*)p;    p += NF * 2;      // x @ gw_w (fp16)
    __half* xh    = (__half*)p;    p += NF * 2;      // normalized mean (fp16)
    char* tail = p;
    __half* z0h   = (__half*)p;    p += NF * 2;
    __half* z1h   = (__half*)p;    p += NF * 2;
    __half* t1h   = (__half*)p;    p += NF * 2;      // op1 result (fp16)
    int*    ptrA  = (int*)p;       p += (size_t)(N + 1) * 4;
    int*    ptrB  = (int*)p;       p += (size_t)(N + 1) * 4;
    int*    curA  = (int*)p;       p += (size_t)N * 4;
    int*    curB  = (int*)p;       p += (size_t)N * 4;
    int*    bsum  = (int*)p;       p += (size_t)nblk * 4;
    int*    bofs  = (int*)p;       p += (size_t)(nblk + 1) * 4;
    p = (char*)(((uintptr_t)p + 7) & ~(uintptr_t)7);
    unsigned long long* cpairA = (unsigned long long*)p; p += (size_t)MAXNNZ * 8;
    unsigned long long* cpairB = (unsigned long long*)p; p += (size_t)MAXNNZ * 8;
    const size_t need_csr = p - (char*)d_ws;
    const bool csr_ok = (ws_size >= need_csr);
    int* ptrS[2] = {ptrA, ptrB};
    int* curS[2] = {curA, curB};
    unsigned long long* cpairS[2] = {cpairA, cpairB};
    (void)n_in; (void)out_size;

    // --- degree / dinv (over edge cols, +1 self-loop); dinv zeroes cnt ---
    (void)hipMemsetAsync(cnt, 0, (size_t)N * sizeof(int), stream);
    hist_kernel<<<(E + 255) / 256, 256, 0, stream>>>(edge_index + E, cnt, E);
    dinv_kernel<<<(N + 255) / 256, 256, 0, stream>>>(cnt, dinv, N);

    // --- dual GEMM: mean0(prenorm,fp32) -> out1 ; xw(fp16) -> xwh ---
    gemm_fused<<<dim3((N + 63) / 64, 4), 256, 0, stream>>>(
        x, lin_w, lin_b, gw_w, out1, xwh, N);
    rownorm_kernel<<<(N + 3) / 4, 256, 0, stream>>>(out1, xh, N);

    if (csr_ok) {
        // op table: [APPNP, A0, B0, A1, B1, A2, B2]
        struct Op {
            const int* rows; const int* cols; const float* vals;
            int mode; int nnz;
            const __half* src; const float* init_src;
            float* dstf; __half* dsth;
        } ops[7];
        ops[0] = {edge_index, edge_index + E, nullptr, 2, E,
                  xh, out1, out0, nullptr};
        for (int i = 0; i < 3; ++i) {
            const int* ri1 = phi_inv_idx + (size_t)i * 2 * NNZ;
            const int* ri2 = phi_idx + (size_t)i * 2 * NNZ;
            ops[1 + 2 * i] = {ri1, ri1 + NNZ, phi_inv_vals + (size_t)i * NNZ,
                              0, NNZ, xwh, nullptr, nullptr, t1h};
            float*  bf = (i == 2) ? out1 : nullptr;
            __half* bh = (i == 0) ? z0h : (i == 1) ? z1h : nullptr;
            ops[2 + 2 * i] = {ri2, ri2 + NNZ, phi_vals + (size_t)i * NNZ,
                              1, NNZ, t1h, nullptr, bf, bh};
        }

        auto scans = [&](int k) {   // cnt -> ptr/cursor[k&1]; zeroes cnt
            scan_reduce_kernel<<<nblk, 256, 0, stream>>>(cnt, bsum, N);
            scan_bsum_kernel<<<1, 64, 0, stream>>>(bsum, bofs, ptrS[k & 1], nblk, N);
            scan_block_kernel<<<nblk, 256, 0, stream>>>(cnt, bofs, ptrS[k & 1],
                                                        curS[k & 1], N);
        };

        const int GRID = 2048;
        // prologue: hist0; scans0; [build0 || hist1] (mix=2: 12B/4H); scans1
        hist_kernel<<<(ops[0].nnz + 255) / 256, 256, 0, stream>>>(
            ops[0].rows, cnt, ops[0].nnz);
        scans(0);
        fused_pipe_kernel<<<GRID, 256, 0, stream>>>(
            nullptr, nullptr, nullptr, nullptr, dinv, nullptr, nullptr, N, 0,
            ops[0].rows, ops[0].cols, ops[0].vals, diag_w, curS[0], cpairS[0],
            ops[0].nnz, ops[0].mode,
            ops[1].rows, cnt, ops[1].nnz, 2);
        scans(1);

        // steady state: F_k = gather_k || build_{k+1} || hist_{k+2}
        for (int k = 0; k < 7; ++k) {
            const Op& g = ops[k];
            const bool hb = (k < 6), hh = (k < 5);
            const Op* b = hb ? &ops[k + 1] : nullptr;
            fused_pipe_kernel<<<GRID, 256, 0, stream>>>(
                ptrS[k & 1], (const int2*)cpairS[k & 1], g.src, g.init_src,
                dinv, g.dstf, g.dsth, N, g.nnz,
                hb ? b->rows : nullptr, hb ? b->cols : nullptr,
                hb ? b->vals : nullptr, diag_w,
                hb ? curS[(k + 1) & 1] : nullptr,
                hb ? cpairS[(k + 1) & 1] : nullptr,
                hb ? b->nnz : 0, hb ? b->mode : 0,
                hh ? ops[k + 2].rows : nullptr, cnt, hh ? ops[k + 2].nnz : 0,
                hb ? 1 : 0);
            if (hh) scans(k + 2);
        }

        // --- attention pooling, in place: out1 = pool(z0h, z1h, out1) ---
        attn_h_kernel<<<2048, 256, 0, stream>>>(z0h, z1h, out1, att_w1, att_b1,
                                                att_w2, out1, N);
    } else {
        // --------- fallback: atomic scatter path (fp32 z) ---------
        float*  z0f  = (float*)tail;
        float*  z1f  = z0f + NF;
        float*  t1f  = z1f + NF;
        __half* t1hf = (__half*)(t1f + NF);
        for (int i = 0; i < 3; ++i) {
            const int* ri1 = phi_inv_idx + (size_t)i * 2 * NNZ;
            const int* ci1 = ri1 + NNZ;
            const int* ri2 = phi_idx + (size_t)i * 2 * NNZ;
            const int* ci2 = ri2 + NNZ;
            float* zdst = (i == 0) ? z0f : (i == 1) ? z1f : out0;

            (void)hipMemsetAsync(t1f, 0, NF * sizeof(float), stream);
            spmm_h_kernel<<<(NNZ + 3) / 4, 256, 0, stream>>>(
                ri1, ci1, phi_inv_vals + (size_t)i * NNZ, nullptr, xwh, t1f, NNZ);
            f2h_kernel<<<((NF / 2) + 255) / 256, 256, 0, stream>>>(t1f, t1hf,
                                                                   NF / 2);
            (void)hipMemsetAsync(zdst, 0, NF * sizeof(float), stream);
            spmm_h_kernel<<<(NNZ + 3) / 4, 256, 0, stream>>>(
                ri2, ci2, phi_vals + (size_t)i * NNZ, diag_w, t1hf, zdst, NNZ);
        }
        attn_f_kernel<<<2048, 256, 0, stream>>>(z0f, z1f, out0, att_w1, att_b1,
                                                att_w2, t1f, N);
        appnp_init_kernel<<<((size_t)N * 32 + 255) / 256, 256, 0, stream>>>(
            out1, dinv, out0, N);
        appnp_edge_h_kernel<<<(E + 3) / 4, 256, 0, stream>>>(
            edge_index, edge_index + E, dinv, xh, out0, E);
        (void)hipMemcpyAsync(out1, t1f, NF * sizeof(float),
                             hipMemcpyDeviceToDevice, stream);
    }
}

// Round 15
// 3317.890 us; speedup vs baseline: 1.0143x; 1.0143x over previous
//
#include <hip/hip_runtime.h>
#include <hip/hip_bf16.h>
#include <hip/hip_fp16.h>

// ---------------------------------------------------------------------------
// Encoder: mean = APPNP(normalize(x@lin_w+b)*1.8), logstd = attention-pooled
// graph-wavelet branch.
// Round 15: r13 (2929us) with finer 32-slot steady mix 18G/11B/3H.
// Model (r13+r14): C_gather=2696 us-slots, C_build=1668 us-slots, both ~1/slots
// -> balanced at ~303us/dispatch (vs 337 at 8/6/2).
// ---------------------------------------------------------------------------

// steady mix (of 32 slots per group)
#define SG 18
#define SB 11
#define SH 3

// ---------- standalone histogram (int atomics) ----------
__global__ __launch_bounds__(256) void hist_kernel(const int* __restrict__ idx,
                                                   int* __restrict__ cnt, int n) {
    int i = blockIdx.x * 256 + threadIdx.x;
    if (i < n) atomicAdd(&cnt[__builtin_nontemporal_load(idx + i)], 1);
}

// dinv from degree; zeroes cnt for the next histogram
__global__ __launch_bounds__(256) void dinv_kernel(int* __restrict__ cnt,
                                                   float* __restrict__ dinv, int n) {
    int i = blockIdx.x * 256 + threadIdx.x;
    if (i < n) { dinv[i] = rsqrtf((float)(cnt[i] + 1)); cnt[i] = 0; }
}

// ---------- 3-kernel exclusive scan of cnt[N] -> ptr[N+1] (chunks of 1024) --
__global__ __launch_bounds__(256) void scan_reduce_kernel(
    const int* __restrict__ cnt, int* __restrict__ bsum, int N) {
    __shared__ int wsum[4];
    int base = blockIdx.x * 1024;
    int t = threadIdx.x;
    int s = 0;
#pragma unroll
    for (int j = 0; j < 4; ++j) {
        int idx = base + t * 4 + j;
        if (idx < N) s += cnt[idx];
    }
#pragma unroll
    for (int off = 32; off; off >>= 1) s += __shfl_xor(s, off);
    int lane = t & 63, w = t >> 6;
    if (lane == 0) wsum[w] = s;
    __syncthreads();
    if (t == 0) bsum[blockIdx.x] = wsum[0] + wsum[1] + wsum[2] + wsum[3];
}

// serial scan of block sums (nblk ~98). bsum and bofs MUST be distinct.
__global__ void scan_bsum_kernel(const int* __restrict__ bsum,
                                 int* __restrict__ bofs,
                                 int* __restrict__ ptr, int nblk, int N) {
    if (threadIdx.x == 0 && blockIdx.x == 0) {
        int run = 0;
        for (int i = 0; i < nblk; ++i) { bofs[i] = run; run += bsum[i]; }
        bofs[nblk] = run;
        ptr[N] = run;
    }
}

// writes ptr/cursor AND zeroes cnt for the next histogram
__global__ __launch_bounds__(256) void scan_block_kernel(
    int* __restrict__ cnt, const int* __restrict__ bofs,
    int* __restrict__ ptr, int* __restrict__ cursor, int N) {
    __shared__ int wsum[4];
    int base = blockIdx.x * 1024;
    int t = threadIdx.x, lane = t & 63, w = t >> 6;
    int v[4]; int s = 0;
#pragma unroll
    for (int j = 0; j < 4; ++j) {
        int idx = base + t * 4 + j;
        v[j] = (idx < N) ? cnt[idx] : 0;
        s += v[j];
    }
    int incl = s;
#pragma unroll
    for (int off = 1; off < 64; off <<= 1) {
        int nn = __shfl_up(incl, off);
        if (lane >= off) incl += nn;
    }
    if (lane == 63) wsum[w] = incl;
    __syncthreads();
    int wofs = 0;
    for (int i = 0; i < w; ++i) wofs += wsum[i];
    int run = bofs[blockIdx.x] + wofs + incl - s;
#pragma unroll
    for (int j = 0; j < 4; ++j) {
        int idx = base + t * 4 + j;
        if (idx < N) { ptr[idx] = run; cursor[idx] = run; cnt[idx] = 0; }
        run += v[j];
    }
}

// ---------- fused pipeline kernel: gather(k) || build(k+1) || hist(k+2) -----
// build modes: 0: v=vals[e]; 1: v=vals[e]*diag[c]; 2: v=dinv[r]*dinv[c]
// cpair u64: hi32 = val bits, lo32 = col  (int2: x=col, y=val)
// mix: 0 = all-gather, 1 = steady 18G/11B/3H (32-slot), 2 = prologue 12B/4H
__global__ __launch_bounds__(256) void fused_pipe_kernel(
    // gather role
    const int* __restrict__ ptr_g, const int2* __restrict__ cpair_g,
    const __half* __restrict__ src, const float* __restrict__ init_src,
    const float* __restrict__ dinv,
    float* __restrict__ dstf, __half* __restrict__ dsth, int N, int nnz_g,
    // build role
    const int* __restrict__ rows_b, const int* __restrict__ cols_b,
    const float* __restrict__ vals_b, const float* __restrict__ diag,
    int* __restrict__ cursor_b, unsigned long long* __restrict__ cpair_b,
    int nnz_b, int mode,
    // hist role
    const int* __restrict__ rows_h, int* __restrict__ cnt, int nnz_h,
    int mix)
{
    int role, lid, nloc;
    if (mix == 0) { role = 2; lid = blockIdx.x; nloc = gridDim.x; }
    else if (mix == 2) {
        int r = blockIdx.x & 15, g = blockIdx.x >> 4, ng = gridDim.x >> 4;
        if (r < 12) { role = 1; lid = g * 12 + r;        nloc = ng * 12; }
        else        { role = 0; lid = g * 4 + (r - 12);  nloc = ng * 4; }
    } else {
        int r = blockIdx.x & 31, g = blockIdx.x >> 5, ng = gridDim.x >> 5;
        if (r < SG)           { role = 2; lid = g * SG + r;          nloc = ng * SG; }
        else if (r < SG + SB) { role = 1; lid = g * SB + (r - SG);   nloc = ng * SB; }
        else                  { role = 0; lid = g * SH + (r - SG - SB); nloc = ng * SH; }
    }

    if (role == 0) {                       // ---- histogram (op k+2) ----
        if (!rows_h) return;
        int stride = nloc * 256;
        for (int i = lid * 256 + threadIdx.x; i < nnz_h; i += stride)
            atomicAdd(&cnt[__builtin_nontemporal_load(rows_h + i)], 1);
        return;
    }
    if (role == 1) {                       // ---- CSR build (op k+1) ----
        if (!rows_b) return;
        int stride = nloc * 256;
        for (int i = lid * 256 + threadIdx.x; i < nnz_b; i += stride) {
            int r = __builtin_nontemporal_load(rows_b + i);
            int c = __builtin_nontemporal_load(cols_b + i);
            float v;
            if (mode == 2) v = dinv[r] * dinv[c];
            else {
                v = __builtin_nontemporal_load(vals_b + i);
                if (mode == 1) v *= diag[c];
            }
            int pos = atomicAdd(&cursor_b[r], 1);
            unsigned long long pk =
                ((unsigned long long)(unsigned)__float_as_uint(v) << 32) | (unsigned)c;
            __builtin_nontemporal_store(pk, cpair_b + pos);
        }
        return;
    }

    // ---- gather (op k): wave per row, 16-deep load pipeline ----
    if (!ptr_g) return;
    const int lane = threadIdx.x & 63;
    const size_t lofs = (size_t)(lane * 2);
    int wid = (lid * 256 + threadIdx.x) >> 6;
    const int nwaves = (nloc * 256) >> 6;
    for (int row = wid; row < N; row += nwaves) {
        int s = ptr_g[row], e = ptr_g[row + 1];
        e = min(e, nnz_g); s = max(0, min(s, e));   // bad CSR must not fault
        float accx = 0.f, accy = 0.f;
        if (init_src) {
            float d = dinv[row];
            float dd = d * d;
            float2 m = *(const float2*)(init_src + (size_t)row * 128 + lofs);
            accx = dd * m.x; accy = dd * m.y;
        }
        for (int base = s; base < e; base += 64) {
            int n = min(64, e - base);
            int2 p = make_int2(0, 0);
            if (lane < n) p = cpair_g[base + lane];
            int j = 0;
            for (; j + 16 <= n; j += 16) {
                __half2 sv[16];
                float vj[16];
#pragma unroll
                for (int u = 0; u < 16; ++u) {
                    int cj = __builtin_amdgcn_readlane(p.x, j + u);
                    vj[u] = __int_as_float(__builtin_amdgcn_readlane(p.y, j + u));
                    sv[u] = *(const __half2*)(src + (size_t)cj * 128 + lofs);
                }
#pragma unroll
                for (int u = 0; u < 16; ++u) {
                    accx += vj[u] * __low2float(sv[u]);
                    accy += vj[u] * __high2float(sv[u]);
                }
            }
            for (; j + 4 <= n; j += 4) {
                __half2 sv[4];
                float vj[4];
#pragma unroll
                for (int u = 0; u < 4; ++u) {
                    int cj = __builtin_amdgcn_readlane(p.x, j + u);
                    vj[u] = __int_as_float(__builtin_amdgcn_readlane(p.y, j + u));
                    sv[u] = *(const __half2*)(src + (size_t)cj * 128 + lofs);
                }
#pragma unroll
                for (int u = 0; u < 4; ++u) {
                    accx += vj[u] * __low2float(sv[u]);
                    accy += vj[u] * __high2float(sv[u]);
                }
            }
            for (; j < n; ++j) {
                int cj = __builtin_amdgcn_readlane(p.x, j);
                float vj = __int_as_float(__builtin_amdgcn_readlane(p.y, j));
                __half2 sv = *(const __half2*)(src + (size_t)cj * 128 + lofs);
                accx += vj * __low2float(sv);
                accy += vj * __high2float(sv);
            }
        }
        if (dstf) {
            float2 o; o.x = accx; o.y = accy;
            *(float2*)(dstf + (size_t)row * 128 + lofs) = o;
        }
        if (dsth) {
            *(__half2*)(dsth + (size_t)row * 128 + lofs) =
                __floats2half2_rn(accx, accy);
        }
    }
}

// ---------- fused dual GEMM: mean0(fp32) = x@lin_w + b, xw(fp16) = x@gw_w ---
__global__ __launch_bounds__(256) void gemm_fused(
    const float* __restrict__ x, const float* __restrict__ lin_w,
    const float* __restrict__ lin_b, const float* __restrict__ gw_w,
    float* __restrict__ mean0, __half* __restrict__ xwh, int M) {
    __shared__ float As[32][68];
    __shared__ float Bs[32][64];
    const int tid = threadIdx.x;
    const int tx = tid & 15, ty = tid >> 4;
    const int row0 = blockIdx.x * 64;
    const int nt = blockIdx.y;
    const float* __restrict__ W = (nt < 2) ? lin_w : gw_w;
    const int colbase = (nt & 1) * 64;

    const int ar = tid >> 3;
    const int ac = (tid & 7) << 2;
    const int bk = tid >> 4;
    const int bn = (tid & 15) << 2;

    float acc[4][4] = {};

    for (int kt = 0; kt < 256; kt += 32) {
#pragma unroll
        for (int rr = 0; rr < 2; ++rr) {
            int r = ar + rr * 32;
            int grow = row0 + r;
            float4 v = make_float4(0.f, 0.f, 0.f, 0.f);
            if (grow < M) v = *(const float4*)(x + (size_t)grow * 256 + kt + ac);
            As[ac + 0][r] = v.x; As[ac + 1][r] = v.y;
            As[ac + 2][r] = v.z; As[ac + 3][r] = v.w;
        }
#pragma unroll
        for (int rr = 0; rr < 2; ++rr) {
            int k = bk + rr * 16;
            *(float4*)&Bs[k][bn] =
                *(const float4*)(W + (size_t)(kt + k) * 128 + colbase + bn);
        }
        __syncthreads();
#pragma unroll
        for (int k = 0; k < 32; ++k) {
            float4 a = *(const float4*)&As[k][ty * 4];
            float4 b = *(const float4*)&Bs[k][tx * 4];
            float av[4] = {a.x, a.y, a.z, a.w};
            float bv[4] = {b.x, b.y, b.z, b.w};
#pragma unroll
            for (int i = 0; i < 4; ++i)
#pragma unroll
                for (int j = 0; j < 4; ++j) acc[i][j] += av[i] * bv[j];
        }
        __syncthreads();
    }

    if (nt < 2) {
        float4 bb = *(const float4*)(lin_b + colbase + tx * 4);
#pragma unroll
        for (int i = 0; i < 4; ++i) {
            int grow = row0 + ty * 4 + i;
            if (grow < M) {
                float4 o = make_float4(acc[i][0] + bb.x, acc[i][1] + bb.y,
                                       acc[i][2] + bb.z, acc[i][3] + bb.w);
                *(float4*)(mean0 + (size_t)grow * 128 + colbase + tx * 4) = o;
            }
        }
    } else {
#pragma unroll
        for (int i = 0; i < 4; ++i) {
            int grow = row0 + ty * 4 + i;
            if (grow < M) {
                union { __half2 h[2]; int2 i2; } u;
                u.h[0] = __floats2half2_rn(acc[i][0], acc[i][1]);
                u.h[1] = __floats2half2_rn(acc[i][2], acc[i][3]);
                *(int2*)(xwh + (size_t)grow * 128 + colbase + tx * 4) = u.i2;
            }
        }
    }
}

// ---------- row L2-normalize * 1.8 in place + fp16 copy (wave per row) -----
__global__ __launch_bounds__(256) void rownorm_kernel(float* __restrict__ m,
                                                      __half* __restrict__ mh,
                                                      int n) {
    const int lane = threadIdx.x & 63;
    int wid = (blockIdx.x * 256 + threadIdx.x) >> 6;
    if (wid >= n) return;
    float2 v = *(float2*)(m + (size_t)wid * 128 + lane * 2);
    float ss = v.x * v.x + v.y * v.y;
#pragma unroll
    for (int off = 32; off; off >>= 1) ss += __shfl_xor(ss, off);
    float s = sqrtf(ss);
    float sc = 1.8f / fmaxf(s, 1e-12f);
    v.x *= sc; v.y *= sc;
    *(float2*)(m + (size_t)wid * 128 + lane * 2) = v;
    *(__half2*)(mh + (size_t)wid * 128 + lane * 2) = __floats2half2_rn(v.x, v.y);
}

// ---------- attention pool, fp16 z0/z1 + fp32 z2, in-place on z2 ----------
__global__ __launch_bounds__(256) void attn_h_kernel(
    const __half* __restrict__ z0, const __half* __restrict__ z1,
    const float* __restrict__ z2, const float* __restrict__ w1,
    const float* __restrict__ b1, const float* __restrict__ w2,
    float* __restrict__ out, int n) {
    const int lane = threadIdx.x & 63;
    float w1reg[128];
#pragma unroll
    for (int d = 0; d < 128; ++d) w1reg[d] = w1[d * 64 + lane];
    const float b1l = b1[lane];
    const float w2l = w2[lane];

    int wid = (blockIdx.x * 256 + threadIdx.x) >> 6;
    const int nwaves = (gridDim.x * 256) >> 6;
    for (int node = wid; node < n; node += nwaves) {
        float2 za = __half22float2(*(const __half2*)(z0 + (size_t)node * 128 + lane * 2));
        float2 zb = __half22float2(*(const __half2*)(z1 + (size_t)node * 128 + lane * 2));
        float2 zc = *(const float2*)(z2 + (size_t)node * 128 + lane * 2);
        float wk[3];
#pragma unroll
        for (int k = 0; k < 3; ++k) {
            float zx = (k == 0) ? za.x : (k == 1) ? zb.x : zc.x;
            float zy = (k == 0) ? za.y : (k == 1) ? zb.y : zc.y;
            float acc = 0.f;
#pragma unroll
            for (int d2 = 0; d2 < 64; ++d2) {
                float ze = __uint_as_float(__builtin_amdgcn_readlane(__float_as_uint(zx), d2));
                float zo = __uint_as_float(__builtin_amdgcn_readlane(__float_as_uint(zy), d2));
                acc += ze * w1reg[2 * d2] + zo * w1reg[2 * d2 + 1];
            }
            float h = fmaxf(acc + b1l, 0.f) * w2l;
#pragma unroll
            for (int off = 32; off; off >>= 1) h += __shfl_xor(h, off);
            wk[k] = h;
        }
        float mx = fmaxf(wk[0], fmaxf(wk[1], wk[2]));
        float e0 = __expf(wk[0] - mx);
        float e1 = __expf(wk[1] - mx);
        float e2 = __expf(wk[2] - mx);
        float inv = 1.f / (e0 + e1 + e2);
        float be0 = e0 * inv, be1 = e1 * inv, be2 = e2 * inv;
        float2 o;
        o.x = be0 * za.x + be1 * zb.x + be2 * zc.x;
        o.y = be0 * za.y + be1 * zb.y + be2 * zc.y;
        *(float2*)(out + (size_t)node * 128 + lane * 2) = o;
    }
}

// ---------- fallback-only kernels (atomic scatter path, fp32 z) ----------
__global__ __launch_bounds__(256) void f2h_kernel(const float* __restrict__ in,
                                                  __half* __restrict__ out,
                                                  size_t n2) {
    size_t i = (size_t)blockIdx.x * 256 + threadIdx.x;
    if (i >= n2) return;
    float2 v = ((const float2*)in)[i];
    ((__half2*)out)[i] = __floats2half2_rn(v.x, v.y);
}

__global__ __launch_bounds__(256) void spmm_h_kernel(
    const int* __restrict__ rows, const int* __restrict__ cols,
    const float* __restrict__ vals, const float* __restrict__ diag,
    const __half* __restrict__ src, float* __restrict__ dst, int nnz) {
    const int lane = threadIdx.x & 63;
    int wid = (blockIdx.x * 256 + threadIdx.x) >> 6;
    const int nwaves = (gridDim.x * 256) >> 6;
    for (int e = wid; e < nnz; e += nwaves) {
        int r = rows[e];
        int c = cols[e];
        float v = vals ? vals[e] : 1.f;
        if (diag) v *= diag[c];
        __half2 sh = *(const __half2*)(src + (size_t)c * 128 + lane * 2);
        float* d = dst + (size_t)r * 128 + lane * 2;
        unsafeAtomicAdd(d,     v * __low2float(sh));
        unsafeAtomicAdd(d + 1, v * __high2float(sh));
    }
}

__global__ __launch_bounds__(256) void appnp_init_kernel(
    const float* __restrict__ mean0, const float* __restrict__ dinv,
    float* __restrict__ dst, int n) {
    int i = blockIdx.x * 256 + threadIdx.x;
    if (i >= n * 32) return;
    int node = i >> 5;
    float dv = dinv[node];
    float dd = dv * dv;
    float4 v = ((const float4*)mean0)[i];
    v.x *= dd; v.y *= dd; v.z *= dd; v.w *= dd;
    ((float4*)dst)[i] = v;
}

__global__ __launch_bounds__(256) void appnp_edge_h_kernel(
    const int* __restrict__ rows, const int* __restrict__ cols,
    const float* __restrict__ dinv, const __half* __restrict__ src,
    float* __restrict__ dst, int nnz) {
    const int lane = threadIdx.x & 63;
    int wid = (blockIdx.x * 256 + threadIdx.x) >> 6;
    const int nwaves = (gridDim.x * 256) >> 6;
    for (int e = wid; e < nnz; e += nwaves) {
        int r = rows[e];
        int c = cols[e];
        float v = dinv[r] * dinv[c];
        __half2 sh = *(const __half2*)(src + (size_t)c * 128 + lane * 2);
        float* d = dst + (size_t)r * 128 + lane * 2;
        unsafeAtomicAdd(d,     v * __low2float(sh));
        unsafeAtomicAdd(d + 1, v * __high2float(sh));
    }
}

__global__ __launch_bounds__(256) void attn_f_kernel(
    const float* __restrict__ z0, const float* __restrict__ z1,
    const float* __restrict__ z2, const float* __restrict__ w1,
    const float* __restrict__ b1, const float* __restrict__ w2,
    float* __restrict__ out, int n) {
    const int lane = threadIdx.x & 63;
    float w1reg[128];
#pragma unroll
    for (int d = 0; d < 128; ++d) w1reg[d] = w1[d * 64 + lane];
    const float b1l = b1[lane];
    const float w2l = w2[lane];
    int wid = (blockIdx.x * 256 + threadIdx.x) >> 6;
    const int nwaves = (gridDim.x * 256) >> 6;
    for (int node = wid; node < n; node += nwaves) {
        float2 za = *(const float2*)(z0 + (size_t)node * 128 + lane * 2);
        float2 zb = *(const float2*)(z1 + (size_t)node * 128 + lane * 2);
        float2 zc = *(const float2*)(z2 + (size_t)node * 128 + lane * 2);
        float wk[3];
#pragma unroll
        for (int k = 0; k < 3; ++k) {
            float zx = (k == 0) ? za.x : (k == 1) ? zb.x : zc.x;
            float zy = (k == 0) ? za.y : (k == 1) ? zb.y : zc.y;
            float acc = 0.f;
#pragma unroll
            for (int d2 = 0; d2 < 64; ++d2) {
                float ze = __uint_as_float(__builtin_amdgcn_readlane(__float_as_uint(zx), d2));
                float zo = __uint_as_float(__builtin_amdgcn_readlane(__float_as_uint(zy), d2));
                acc += ze * w1reg[2 * d2] + zo * w1reg[2 * d2 + 1];
            }
            float h = fmaxf(acc + b1l, 0.f) * w2l;
#pragma unroll
            for (int off = 32; off; off >>= 1) h += __shfl_xor(h, off);
            wk[k] = h;
        }
        float mx = fmaxf(wk[0], fmaxf(wk[1], wk[2]));
        float e0 = __expf(wk[0] - mx);
        float e1 = __expf(wk[1] - mx);
        float e2 = __expf(wk[2] - mx);
        float inv = 1.f / (e0 + e1 + e2);
        float be0 = e0 * inv, be1 = e1 * inv, be2 = e2 * inv;
        float2 o;
        o.x = be0 * za.x + be1 * zb.x + be2 * zc.x;
        o.y = be0 * za.y + be1 * zb.y + be2 * zc.y;
        *(float2*)(out + (size_t)node * 128 + lane * 2) = o;
    }
}

// ---------------------------------------------------------------------------
extern "C" void kernel_launch(void* const* d_in, const int* in_sizes, int n_in,
                              void* d_out, int out_size, void* d_ws, size_t ws_size,
                              hipStream_t stream)
{
    const float* x            = (const float*)d_in[0];
    const int*   edge_index   = (const int*)d_in[1];    // [2,E]
    const int*   phi_idx      = (const int*)d_in[2];    // [K,2,NNZ]
    const float* phi_vals     = (const float*)d_in[3];  // [K,NNZ]
    const int*   phi_inv_idx  = (const int*)d_in[4];
    const float* phi_inv_vals = (const float*)d_in[5];
    const float* lin_w        = (const float*)d_in[6];
    const float* lin_b        = (const float*)d_in[7];
    const float* gw_w         = (const float*)d_in[8];
    const float* diag_w       = (const float*)d_in[9];
    const float* att_w1       = (const float*)d_in[10];
    const float* att_b1       = (const float*)d_in[11];
    const float* att_w2       = (const float*)d_in[12];

    const int N   = in_sizes[9];
    const int E   = in_sizes[1] / 2;
    const int NNZ = in_sizes[3] / 3;
    const size_t NF = (size_t)N * 128;
    const int MAXNNZ = (E > NNZ) ? E : NNZ;
    const int nblk = (N + 1023) / 1024;

    float* out0 = (float*)d_out;          // final: mean
    float* out1 = out0 + NF;              // final: logstd (temp: mean0, then z2)

    // ---- workspace layout ----
    char* p = (char*)d_ws;
    int*    cnt   = (int*)p;       p += (size_t)N * 4;
    float*  dinv  = (float*)p;     p += (size_t)N * 4;
    __half* xwh   = (__half*)p;    p += NF * 2;      // x @ gw_w (fp16)
    __half* xh    = (__half*)p;    p += NF * 2;      // normalized mean (fp16)
    char* tail = p;
    __half* z0h   = (__half*)p;    p += NF * 2;
    __half* z1h   = (__half*)p;    p += NF * 2;
    __half* t1h   = (__half*)p;    p += NF * 2;      // op1 result (fp16)
    int*    ptrA  = (int*)p;       p += (size_t)(N + 1) * 4;
    int*    ptrB  = (int*)p;       p += (size_t)(N + 1) * 4;
    int*    curA  = (int*)p;       p += (size_t)N * 4;
    int*    curB  = (int*)p;       p += (size_t)N * 4;
    int*    bsum  = (int*)p;       p += (size_t)nblk * 4;
    int*    bofs  = (int*)p;       p += (size_t)(nblk + 1) * 4;
    p = (char*)(((uintptr_t)p + 7) & ~(uintptr_t)7);
    unsigned long long* cpairA = (unsigned long long*)p; p += (size_t)MAXNNZ * 8;
    unsigned long long* cpairB = (unsigned long long*)p; p += (size_t)MAXNNZ * 8;
    const size_t need_csr = p - (char*)d_ws;
    const bool csr_ok = (ws_size >= need_csr);
    int* ptrS[2] = {ptrA, ptrB};
    int* curS[2] = {curA, curB};
    unsigned long long* cpairS[2] = {cpairA, cpairB};
    (void)n_in; (void)out_size;

    // --- degree / dinv (over edge cols, +1 self-loop); dinv zeroes cnt ---
    (void)hipMemsetAsync(cnt, 0, (size_t)N * sizeof(int), stream);
    hist_kernel<<<(E + 255) / 256, 256, 0, stream>>>(edge_index + E, cnt, E);
    dinv_kernel<<<(N + 255) / 256, 256, 0, stream>>>(cnt, dinv, N);

    // --- dual GEMM: mean0(prenorm,fp32) -> out1 ; xw(fp16) -> xwh ---
    gemm_fused<<<dim3((N + 63) / 64, 4), 256, 0, stream>>>(
        x, lin_w, lin_b, gw_w, out1, xwh, N);
    rownorm_kernel<<<(N + 3) / 4, 256, 0, stream>>>(out1, xh, N);

    if (csr_ok) {
        // op table: [APPNP, A0, B0, A1, B1, A2, B2]
        struct Op {
            const int* rows; const int* cols; const float* vals;
            int mode; int nnz;
            const __half* src; const float* init_src;
            float* dstf; __half* dsth;
        } ops[7];
        ops[0] = {edge_index, edge_index + E, nullptr, 2, E,
                  xh, out1, out0, nullptr};
        for (int i = 0; i < 3; ++i) {
            const int* ri1 = phi_inv_idx + (size_t)i * 2 * NNZ;
            const int* ri2 = phi_idx + (size_t)i * 2 * NNZ;
            ops[1 + 2 * i] = {ri1, ri1 + NNZ, phi_inv_vals + (size_t)i * NNZ,
                              0, NNZ, xwh, nullptr, nullptr, t1h};
            float*  bf = (i == 2) ? out1 : nullptr;
            __half* bh = (i == 0) ? z0h : (i == 1) ? z1h : nullptr;
            ops[2 + 2 * i] = {ri2, ri2 + NNZ, phi_vals + (size_t)i * NNZ,
                              1, NNZ, t1h, nullptr, bf, bh};
        }

        auto scans = [&](int k) {   // cnt -> ptr/cursor[k&1]; zeroes cnt
            scan_reduce_kernel<<<nblk, 256, 0, stream>>>(cnt, bsum, N);
            scan_bsum_kernel<<<1, 64, 0, stream>>>(bsum, bofs, ptrS[k & 1], nblk, N);
            scan_block_kernel<<<nblk, 256, 0, stream>>>(cnt, bofs, ptrS[k & 1],
                                                        curS[k & 1], N);
        };

        const int GRID = 2048;   // multiple of 32 (steady) and 16 (prologue)
        // prologue: hist0; scans0; [build0 || hist1] (mix=2: 12B/4H); scans1
        hist_kernel<<<(ops[0].nnz + 255) / 256, 256, 0, stream>>>(
            ops[0].rows, cnt, ops[0].nnz);
        scans(0);
        fused_pipe_kernel<<<GRID, 256, 0, stream>>>(
            nullptr, nullptr, nullptr, nullptr, dinv, nullptr, nullptr, N, 0,
            ops[0].rows, ops[0].cols, ops[0].vals, diag_w, curS[0], cpairS[0],
            ops[0].nnz, ops[0].mode,
            ops[1].rows, cnt, ops[1].nnz, 2);
        scans(1);

        // steady state: F_k = gather_k || build_{k+1} || hist_{k+2}
        for (int k = 0; k < 7; ++k) {
            const Op& g = ops[k];
            const bool hb = (k < 6), hh = (k < 5);
            const Op* b = hb ? &ops[k + 1] : nullptr;
            fused_pipe_kernel<<<GRID, 256, 0, stream>>>(
                ptrS[k & 1], (const int2*)cpairS[k & 1], g.src, g.init_src,
                dinv, g.dstf, g.dsth, N, g.nnz,
                hb ? b->rows : nullptr, hb ? b->cols : nullptr,
                hb ? b->vals : nullptr, diag_w,
                hb ? curS[(k + 1) & 1] : nullptr,
                hb ? cpairS[(k + 1) & 1] : nullptr,
                hb ? b->nnz : 0, hb ? b->mode : 0,
                hh ? ops[k + 2].rows : nullptr, cnt, hh ? ops[k + 2].nnz : 0,
                hb ? 1 : 0);
            if (hh) scans(k + 2);
        }

        // --- attention pooling, in place: out1 = pool(z0h, z1h, out1) ---
        attn_h_kernel<<<2048, 256, 0, stream>>>(z0h, z1h, out1, att_w1, att_b1,
                                                att_w2, out1, N);
    } else {
        // --------- fallback: atomic scatter path (fp32 z) ---------
        float*  z0f  = (float*)tail;
        float*  z1f  = z0f + NF;
        float*  t1f  = z1f + NF;
        __half* t1hf = (__half*)(t1f + NF);
        for (int i = 0; i < 3; ++i) {
            const int* ri1 = phi_inv_idx + (size_t)i * 2 * NNZ;
            const int* ci1 = ri1 + NNZ;
            const int* ri2 = phi_idx + (size_t)i * 2 * NNZ;
            const int* ci2 = ri2 + NNZ;
            float* zdst = (i == 0) ? z0f : (i == 1) ? z1f : out0;

            (void)hipMemsetAsync(t1f, 0, NF * sizeof(float), stream);
            spmm_h_kernel<<<(NNZ + 3) / 4, 256, 0, stream>>>(
                ri1, ci1, phi_inv_vals + (size_t)i * NNZ, nullptr, xwh, t1f, NNZ);
            f2h_kernel<<<((NF / 2) + 255) / 256, 256, 0, stream>>>(t1f, t1hf,
                                                                   NF / 2);
            (void)hipMemsetAsync(zdst, 0, NF * sizeof(float), stream);
            spmm_h_kernel<<<(NNZ + 3) / 4, 256, 0, stream>>>(
                ri2, ci2, phi_vals + (size_t)i * NNZ, diag_w, t1hf, zdst, NNZ);
        }
        attn_f_kernel<<<2048, 256, 0, stream>>>(z0f, z1f, out0, att_w1, att_b1,
                                                att_w2, t1f, N);
        appnp_init_kernel<<<((size_t)N * 32 + 255) / 256, 256, 0, stream>>>(
            out1, dinv, out0, N);
        appnp_edge_h_kernel<<<(E + 3) / 4, 256, 0, stream>>>(
            edge_index, edge_index + E, dinv, xh, out0, E);
        (void)hipMemcpyAsync(out1, t1f, NF * sizeof(float),
                             hipMemcpyDeviceToDevice, stream);
    }
}

// Round 16
// 2928.639 us; speedup vs baseline: 1.1491x; 1.1329x over previous
//
#include <hip/hip_runtime.h>
#include <hip/hip_bf16.h>
#include <hip/hip_fp16.h>

// ---------------------------------------------------------------------------
// Encoder: mean = APPNP(normalize(x@lin_w+b)*1.8), logstd = attention-pooled
// graph-wavelet branch.
// Round 16: revert to round-13 exactly (best measured: 2929us).
// Slot-balance exploration complete: 8G/6B/2H steady + 12B/4H prologue is the
// empirical optimum (10/4/2 -> 417us/dispatch, 18/11/3 -> 395us; 8/6/2 -> 337).
// ---------------------------------------------------------------------------

#define WS_HIST  2
#define WS_BUILD 6
#define WS_GATH  8   // of 16 slots per blockIdx group (steady state)

// ---------- standalone histogram (int atomics) ----------
__global__ __launch_bounds__(256) void hist_kernel(const int* __restrict__ idx,
                                                   int* __restrict__ cnt, int n) {
    int i = blockIdx.x * 256 + threadIdx.x;
    if (i < n) atomicAdd(&cnt[__builtin_nontemporal_load(idx + i)], 1);
}

// dinv from degree; zeroes cnt for the next histogram
__global__ __launch_bounds__(256) void dinv_kernel(int* __restrict__ cnt,
                                                   float* __restrict__ dinv, int n) {
    int i = blockIdx.x * 256 + threadIdx.x;
    if (i < n) { dinv[i] = rsqrtf((float)(cnt[i] + 1)); cnt[i] = 0; }
}

// ---------- 3-kernel exclusive scan of cnt[N] -> ptr[N+1] (chunks of 1024) --
__global__ __launch_bounds__(256) void scan_reduce_kernel(
    const int* __restrict__ cnt, int* __restrict__ bsum, int N) {
    __shared__ int wsum[4];
    int base = blockIdx.x * 1024;
    int t = threadIdx.x;
    int s = 0;
#pragma unroll
    for (int j = 0; j < 4; ++j) {
        int idx = base + t * 4 + j;
        if (idx < N) s += cnt[idx];
    }
#pragma unroll
    for (int off = 32; off; off >>= 1) s += __shfl_xor(s, off);
    int lane = t & 63, w = t >> 6;
    if (lane == 0) wsum[w] = s;
    __syncthreads();
    if (t == 0) bsum[blockIdx.x] = wsum[0] + wsum[1] + wsum[2] + wsum[3];
}

// serial scan of block sums (nblk ~98). bsum and bofs MUST be distinct.
__global__ void scan_bsum_kernel(const int* __restrict__ bsum,
                                 int* __restrict__ bofs,
                                 int* __restrict__ ptr, int nblk, int N) {
    if (threadIdx.x == 0 && blockIdx.x == 0) {
        int run = 0;
        for (int i = 0; i < nblk; ++i) { bofs[i] = run; run += bsum[i]; }
        bofs[nblk] = run;
        ptr[N] = run;
    }
}

// writes ptr/cursor AND zeroes cnt for the next histogram
__global__ __launch_bounds__(256) void scan_block_kernel(
    int* __restrict__ cnt, const int* __restrict__ bofs,
    int* __restrict__ ptr, int* __restrict__ cursor, int N) {
    __shared__ int wsum[4];
    int base = blockIdx.x * 1024;
    int t = threadIdx.x, lane = t & 63, w = t >> 6;
    int v[4]; int s = 0;
#pragma unroll
    for (int j = 0; j < 4; ++j) {
        int idx = base + t * 4 + j;
        v[j] = (idx < N) ? cnt[idx] : 0;
        s += v[j];
    }
    int incl = s;
#pragma unroll
    for (int off = 1; off < 64; off <<= 1) {
        int nn = __shfl_up(incl, off);
        if (lane >= off) incl += nn;
    }
    if (lane == 63) wsum[w] = incl;
    __syncthreads();
    int wofs = 0;
    for (int i = 0; i < w; ++i) wofs += wsum[i];
    int run = bofs[blockIdx.x] + wofs + incl - s;
#pragma unroll
    for (int j = 0; j < 4; ++j) {
        int idx = base + t * 4 + j;
        if (idx < N) { ptr[idx] = run; cursor[idx] = run; cnt[idx] = 0; }
        run += v[j];
    }
}

// ---------- fused pipeline kernel: gather(k) || build(k+1) || hist(k+2) -----
// build modes: 0: v=vals[e]; 1: v=vals[e]*diag[c]; 2: v=dinv[r]*dinv[c]
// cpair u64: hi32 = val bits, lo32 = col  (int2: x=col, y=val)
// mix: 0 = all-gather, 1 = steady 8G/6B/2H, 2 = prologue 12B/4H
__global__ __launch_bounds__(256) void fused_pipe_kernel(
    // gather role
    const int* __restrict__ ptr_g, const int2* __restrict__ cpair_g,
    const __half* __restrict__ src, const float* __restrict__ init_src,
    const float* __restrict__ dinv,
    float* __restrict__ dstf, __half* __restrict__ dsth, int N, int nnz_g,
    // build role
    const int* __restrict__ rows_b, const int* __restrict__ cols_b,
    const float* __restrict__ vals_b, const float* __restrict__ diag,
    int* __restrict__ cursor_b, unsigned long long* __restrict__ cpair_b,
    int nnz_b, int mode,
    // hist role
    const int* __restrict__ rows_h, int* __restrict__ cnt, int nnz_h,
    int mix)
{
    int role, lid, nloc;
    if (mix == 0) { role = 2; lid = blockIdx.x; nloc = gridDim.x; }
    else if (mix == 2) {
        int r = blockIdx.x & 15, g = blockIdx.x >> 4, ng = gridDim.x >> 4;
        if (r < 12) { role = 1; lid = g * 12 + r;        nloc = ng * 12; }
        else        { role = 0; lid = g * 4 + (r - 12);  nloc = ng * 4; }
    } else {
        int r = blockIdx.x & 15, g = blockIdx.x >> 4, ng = gridDim.x >> 4;
        if (r < WS_HIST)                { role = 0; lid = g * WS_HIST + r;                nloc = ng * WS_HIST; }
        else if (r < WS_HIST + WS_BUILD){ role = 1; lid = g * WS_BUILD + (r - WS_HIST);   nloc = ng * WS_BUILD; }
        else                            { role = 2; lid = g * WS_GATH + (r - WS_HIST - WS_BUILD); nloc = ng * WS_GATH; }
    }

    if (role == 0) {                       // ---- histogram (op k+2) ----
        if (!rows_h) return;
        int stride = nloc * 256;
        for (int i = lid * 256 + threadIdx.x; i < nnz_h; i += stride)
            atomicAdd(&cnt[__builtin_nontemporal_load(rows_h + i)], 1);
        return;
    }
    if (role == 1) {                       // ---- CSR build (op k+1) ----
        if (!rows_b) return;
        int stride = nloc * 256;
        for (int i = lid * 256 + threadIdx.x; i < nnz_b; i += stride) {
            int r = __builtin_nontemporal_load(rows_b + i);
            int c = __builtin_nontemporal_load(cols_b + i);
            float v;
            if (mode == 2) v = dinv[r] * dinv[c];
            else {
                v = __builtin_nontemporal_load(vals_b + i);
                if (mode == 1) v *= diag[c];
            }
            int pos = atomicAdd(&cursor_b[r], 1);
            unsigned long long pk =
                ((unsigned long long)(unsigned)__float_as_uint(v) << 32) | (unsigned)c;
            __builtin_nontemporal_store(pk, cpair_b + pos);
        }
        return;
    }

    // ---- gather (op k): wave per row, 16-deep load pipeline ----
    if (!ptr_g) return;
    const int lane = threadIdx.x & 63;
    const size_t lofs = (size_t)(lane * 2);
    int wid = (lid * 256 + threadIdx.x) >> 6;
    const int nwaves = (nloc * 256) >> 6;
    for (int row = wid; row < N; row += nwaves) {
        int s = ptr_g[row], e = ptr_g[row + 1];
        e = min(e, nnz_g); s = max(0, min(s, e));   // bad CSR must not fault
        float accx = 0.f, accy = 0.f;
        if (init_src) {
            float d = dinv[row];
            float dd = d * d;
            float2 m = *(const float2*)(init_src + (size_t)row * 128 + lofs);
            accx = dd * m.x; accy = dd * m.y;
        }
        for (int base = s; base < e; base += 64) {
            int n = min(64, e - base);
            int2 p = make_int2(0, 0);
            if (lane < n) p = cpair_g[base + lane];
            int j = 0;
            for (; j + 16 <= n; j += 16) {
                __half2 sv[16];
                float vj[16];
#pragma unroll
                for (int u = 0; u < 16; ++u) {
                    int cj = __builtin_amdgcn_readlane(p.x, j + u);
                    vj[u] = __int_as_float(__builtin_amdgcn_readlane(p.y, j + u));
                    sv[u] = *(const __half2*)(src + (size_t)cj * 128 + lofs);
                }
#pragma unroll
                for (int u = 0; u < 16; ++u) {
                    accx += vj[u] * __low2float(sv[u]);
                    accy += vj[u] * __high2float(sv[u]);
                }
            }
            for (; j + 4 <= n; j += 4) {
                __half2 sv[4];
                float vj[4];
#pragma unroll
                for (int u = 0; u < 4; ++u) {
                    int cj = __builtin_amdgcn_readlane(p.x, j + u);
                    vj[u] = __int_as_float(__builtin_amdgcn_readlane(p.y, j + u));
                    sv[u] = *(const __half2*)(src + (size_t)cj * 128 + lofs);
                }
#pragma unroll
                for (int u = 0; u < 4; ++u) {
                    accx += vj[u] * __low2float(sv[u]);
                    accy += vj[u] * __high2float(sv[u]);
                }
            }
            for (; j < n; ++j) {
                int cj = __builtin_amdgcn_readlane(p.x, j);
                float vj = __int_as_float(__builtin_amdgcn_readlane(p.y, j));
                __half2 sv = *(const __half2*)(src + (size_t)cj * 128 + lofs);
                accx += vj * __low2float(sv);
                accy += vj * __high2float(sv);
            }
        }
        if (dstf) {
            float2 o; o.x = accx; o.y = accy;
            *(float2*)(dstf + (size_t)row * 128 + lofs) = o;
        }
        if (dsth) {
            *(__half2*)(dsth + (size_t)row * 128 + lofs) =
                __floats2half2_rn(accx, accy);
        }
    }
}

// ---------- fused dual GEMM: mean0(fp32) = x@lin_w + b, xw(fp16) = x@gw_w ---
__global__ __launch_bounds__(256) void gemm_fused(
    const float* __restrict__ x, const float* __restrict__ lin_w,
    const float* __restrict__ lin_b, const float* __restrict__ gw_w,
    float* __restrict__ mean0, __half* __restrict__ xwh, int M) {
    __shared__ float As[32][68];
    __shared__ float Bs[32][64];
    const int tid = threadIdx.x;
    const int tx = tid & 15, ty = tid >> 4;
    const int row0 = blockIdx.x * 64;
    const int nt = blockIdx.y;
    const float* __restrict__ W = (nt < 2) ? lin_w : gw_w;
    const int colbase = (nt & 1) * 64;

    const int ar = tid >> 3;
    const int ac = (tid & 7) << 2;
    const int bk = tid >> 4;
    const int bn = (tid & 15) << 2;

    float acc[4][4] = {};

    for (int kt = 0; kt < 256; kt += 32) {
#pragma unroll
        for (int rr = 0; rr < 2; ++rr) {
            int r = ar + rr * 32;
            int grow = row0 + r;
            float4 v = make_float4(0.f, 0.f, 0.f, 0.f);
            if (grow < M) v = *(const float4*)(x + (size_t)grow * 256 + kt + ac);
            As[ac + 0][r] = v.x; As[ac + 1][r] = v.y;
            As[ac + 2][r] = v.z; As[ac + 3][r] = v.w;
        }
#pragma unroll
        for (int rr = 0; rr < 2; ++rr) {
            int k = bk + rr * 16;
            *(float4*)&Bs[k][bn] =
                *(const float4*)(W + (size_t)(kt + k) * 128 + colbase + bn);
        }
        __syncthreads();
#pragma unroll
        for (int k = 0; k < 32; ++k) {
            float4 a = *(const float4*)&As[k][ty * 4];
            float4 b = *(const float4*)&Bs[k][tx * 4];
            float av[4] = {a.x, a.y, a.z, a.w};
            float bv[4] = {b.x, b.y, b.z, b.w};
#pragma unroll
            for (int i = 0; i < 4; ++i)
#pragma unroll
                for (int j = 0; j < 4; ++j) acc[i][j] += av[i] * bv[j];
        }
        __syncthreads();
    }

    if (nt < 2) {
        float4 bb = *(const float4*)(lin_b + colbase + tx * 4);
#pragma unroll
        for (int i = 0; i < 4; ++i) {
            int grow = row0 + ty * 4 + i;
            if (grow < M) {
                float4 o = make_float4(acc[i][0] + bb.x, acc[i][1] + bb.y,
                                       acc[i][2] + bb.z, acc[i][3] + bb.w);
                *(float4*)(mean0 + (size_t)grow * 128 + colbase + tx * 4) = o;
            }
        }
    } else {
#pragma unroll
        for (int i = 0; i < 4; ++i) {
            int grow = row0 + ty * 4 + i;
            if (grow < M) {
                union { __half2 h[2]; int2 i2; } u;
                u.h[0] = __floats2half2_rn(acc[i][0], acc[i][1]);
                u.h[1] = __floats2half2_rn(acc[i][2], acc[i][3]);
                *(int2*)(xwh + (size_t)grow * 128 + colbase + tx * 4) = u.i2;
            }
        }
    }
}

// ---------- row L2-normalize * 1.8 in place + fp16 copy (wave per row) -----
__global__ __launch_bounds__(256) void rownorm_kernel(float* __restrict__ m,
                                                      __half* __restrict__ mh,
                                                      int n) {
    const int lane = threadIdx.x & 63;
    int wid = (blockIdx.x * 256 + threadIdx.x) >> 6;
    if (wid >= n) return;
    float2 v = *(float2*)(m + (size_t)wid * 128 + lane * 2);
    float ss = v.x * v.x + v.y * v.y;
#pragma unroll
    for (int off = 32; off; off >>= 1) ss += __shfl_xor(ss, off);
    float s = sqrtf(ss);
    float sc = 1.8f / fmaxf(s, 1e-12f);
    v.x *= sc; v.y *= sc;
    *(float2*)(m + (size_t)wid * 128 + lane * 2) = v;
    *(__half2*)(mh + (size_t)wid * 128 + lane * 2) = __floats2half2_rn(v.x, v.y);
}

// ---------- attention pool, fp16 z0/z1 + fp32 z2, in-place on z2 ----------
__global__ __launch_bounds__(256) void attn_h_kernel(
    const __half* __restrict__ z0, const __half* __restrict__ z1,
    const float* __restrict__ z2, const float* __restrict__ w1,
    const float* __restrict__ b1, const float* __restrict__ w2,
    float* __restrict__ out, int n) {
    const int lane = threadIdx.x & 63;
    float w1reg[128];
#pragma unroll
    for (int d = 0; d < 128; ++d) w1reg[d] = w1[d * 64 + lane];
    const float b1l = b1[lane];
    const float w2l = w2[lane];

    int wid = (blockIdx.x * 256 + threadIdx.x) >> 6;
    const int nwaves = (gridDim.x * 256) >> 6;
    for (int node = wid; node < n; node += nwaves) {
        float2 za = __half22float2(*(const __half2*)(z0 + (size_t)node * 128 + lane * 2));
        float2 zb = __half22float2(*(const __half2*)(z1 + (size_t)node * 128 + lane * 2));
        float2 zc = *(const float2*)(z2 + (size_t)node * 128 + lane * 2);
        float wk[3];
#pragma unroll
        for (int k = 0; k < 3; ++k) {
            float zx = (k == 0) ? za.x : (k == 1) ? zb.x : zc.x;
            float zy = (k == 0) ? za.y : (k == 1) ? zb.y : zc.y;
            float acc = 0.f;
#pragma unroll
            for (int d2 = 0; d2 < 64; ++d2) {
                float ze = __uint_as_float(__builtin_amdgcn_readlane(__float_as_uint(zx), d2));
                float zo = __uint_as_float(__builtin_amdgcn_readlane(__float_as_uint(zy), d2));
                acc += ze * w1reg[2 * d2] + zo * w1reg[2 * d2 + 1];
            }
            float h = fmaxf(acc + b1l, 0.f) * w2l;
#pragma unroll
            for (int off = 32; off; off >>= 1) h += __shfl_xor(h, off);
            wk[k] = h;
        }
        float mx = fmaxf(wk[0], fmaxf(wk[1], wk[2]));
        float e0 = __expf(wk[0] - mx);
        float e1 = __expf(wk[1] - mx);
        float e2 = __expf(wk[2] - mx);
        float inv = 1.f / (e0 + e1 + e2);
        float be0 = e0 * inv, be1 = e1 * inv, be2 = e2 * inv;
        float2 o;
        o.x = be0 * za.x + be1 * zb.x + be2 * zc.x;
        o.y = be0 * za.y + be1 * zb.y + be2 * zc.y;
        *(float2*)(out + (size_t)node * 128 + lane * 2) = o;
    }
}

// ---------- fallback-only kernels (atomic scatter path, fp32 z) ----------
__global__ __launch_bounds__(256) void f2h_kernel(const float* __restrict__ in,
                                                  __half* __restrict__ out,
                                                  size_t n2) {
    size_t i = (size_t)blockIdx.x * 256 + threadIdx.x;
    if (i >= n2) return;
    float2 v = ((const float2*)in)[i];
    ((__half2*)out)[i] = __floats2half2_rn(v.x, v.y);
}

__global__ __launch_bounds__(256) void spmm_h_kernel(
    const int* __restrict__ rows, const int* __restrict__ cols,
    const float* __restrict__ vals, const float* __restrict__ diag,
    const __half* __restrict__ src, float* __restrict__ dst, int nnz) {
    const int lane = threadIdx.x & 63;
    int wid = (blockIdx.x * 256 + threadIdx.x) >> 6;
    const int nwaves = (gridDim.x * 256) >> 6;
    for (int e = wid; e < nnz; e += nwaves) {
        int r = rows[e];
        int c = cols[e];
        float v = vals ? vals[e] : 1.f;
        if (diag) v *= diag[c];
        __half2 sh = *(const __half2*)(src + (size_t)c * 128 + lane * 2);
        float* d = dst + (size_t)r * 128 + lane * 2;
        unsafeAtomicAdd(d,     v * __low2float(sh));
        unsafeAtomicAdd(d + 1, v * __high2float(sh));
    }
}

__global__ __launch_bounds__(256) void appnp_init_kernel(
    const float* __restrict__ mean0, const float* __restrict__ dinv,
    float* __restrict__ dst, int n) {
    int i = blockIdx.x * 256 + threadIdx.x;
    if (i >= n * 32) return;
    int node = i >> 5;
    float dv = dinv[node];
    float dd = dv * dv;
    float4 v = ((const float4*)mean0)[i];
    v.x *= dd; v.y *= dd; v.z *= dd; v.w *= dd;
    ((float4*)dst)[i] = v;
}

__global__ __launch_bounds__(256) void appnp_edge_h_kernel(
    const int* __restrict__ rows, const int* __restrict__ cols,
    const float* __restrict__ dinv, const __half* __restrict__ src,
    float* __restrict__ dst, int nnz) {
    const int lane = threadIdx.x & 63;
    int wid = (blockIdx.x * 256 + threadIdx.x) >> 6;
    const int nwaves = (gridDim.x * 256) >> 6;
    for (int e = wid; e < nnz; e += nwaves) {
        int r = rows[e];
        int c = cols[e];
        float v = dinv[r] * dinv[c];
        __half2 sh = *(const __half2*)(src + (size_t)c * 128 + lane * 2);
        float* d = dst + (size_t)r * 128 + lane * 2;
        unsafeAtomicAdd(d,     v * __low2float(sh));
        unsafeAtomicAdd(d + 1, v * __high2float(sh));
    }
}

__global__ __launch_bounds__(256) void attn_f_kernel(
    const float* __restrict__ z0, const float* __restrict__ z1,
    const float* __restrict__ z2, const float* __restrict__ w1,
    const float* __restrict__ b1, const float* __restrict__ w2,
    float* __restrict__ out, int n) {
    const int lane = threadIdx.x & 63;
    float w1reg[128];
#pragma unroll
    for (int d = 0; d < 128; ++d) w1reg[d] = w1[d * 64 + lane];
    const float b1l = b1[lane];
    const float w2l = w2[lane];
    int wid = (blockIdx.x * 256 + threadIdx.x) >> 6;
    const int nwaves = (gridDim.x * 256) >> 6;
    for (int node = wid; node < n; node += nwaves) {
        float2 za = *(const float2*)(z0 + (size_t)node * 128 + lane * 2);
        float2 zb = *(const float2*)(z1 + (size_t)node * 128 + lane * 2);
        float2 zc = *(const float2*)(z2 + (size_t)node * 128 + lane * 2);
        float wk[3];
#pragma unroll
        for (int k = 0; k < 3; ++k) {
            float zx = (k == 0) ? za.x : (k == 1) ? zb.x : zc.x;
            float zy = (k == 0) ? za.y : (k == 1) ? zb.y : zc.y;
            float acc = 0.f;
#pragma unroll
            for (int d2 = 0; d2 < 64; ++d2) {
                float ze = __uint_as_float(__builtin_amdgcn_readlane(__float_as_uint(zx), d2));
                float zo = __uint_as_float(__builtin_amdgcn_readlane(__float_as_uint(zy), d2));
                acc += ze * w1reg[2 * d2] + zo * w1reg[2 * d2 + 1];
            }
            float h = fmaxf(acc + b1l, 0.f) * w2l;
#pragma unroll
            for (int off = 32; off; off >>= 1) h += __shfl_xor(h, off);
            wk[k] = h;
        }
        float mx = fmaxf(wk[0], fmaxf(wk[1], wk[2]));
        float e0 = __expf(wk[0] - mx);
        float e1 = __expf(wk[1] - mx);
        float e2 = __expf(wk[2] - mx);
        float inv = 1.f / (e0 + e1 + e2);
        float be0 = e0 * inv, be1 = e1 * inv, be2 = e2 * inv;
        float2 o;
        o.x = be0 * za.x + be1 * zb.x + be2 * zc.x;
        o.y = be0 * za.y + be1 * zb.y + be2 * zc.y;
        *(float2*)(out + (size_t)node * 128 + lane * 2) = o;
    }
}

// ---------------------------------------------------------------------------
extern "C" void kernel_launch(void* const* d_in, const int* in_sizes, int n_in,
                              void* d_out, int out_size, void* d_ws, size_t ws_size,
                              hipStream_t stream)
{
    const float* x            = (const float*)d_in[0];
    const int*   edge_index   = (const int*)d_in[1];    // [2,E]
    const int*   phi_idx      = (const int*)d_in[2];    // [K,2,NNZ]
    const float* phi_vals     = (const float*)d_in[3];  // [K,NNZ]
    const int*   phi_inv_idx  = (const int*)d_in[4];
    const float* phi_inv_vals = (const float*)d_in[5];
    const float* lin_w        = (const float*)d_in[6];
    const float* lin_b        = (const float*)d_in[7];
    const float* gw_w         = (const float*)d_in[8];
    const float* diag_w       = (const float*)d_in[9];
    const float* att_w1       = (const float*)d_in[10];
    const float* att_b1       = (const float*)d_in[11];
    const float* att_w2       = (const float*)d_in[12];

    const int N   = in_sizes[9];
    const int E   = in_sizes[1] / 2;
    const int NNZ = in_sizes[3] / 3;
    const size_t NF = (size_t)N * 128;
    const int MAXNNZ = (E > NNZ) ? E : NNZ;
    const int nblk = (N + 1023) / 1024;

    float* out0 = (float*)d_out;          // final: mean
    float* out1 = out0 + NF;              // final: logstd (temp: mean0, then z2)

    // ---- workspace layout ----
    char* p = (char*)d_ws;
    int*    cnt   = (int*)p;       p += (size_t)N * 4;
    float*  dinv  = (float*)p;     p += (size_t)N * 4;
    __half* xwh   = (__half*)p;    p += NF * 2;      // x @ gw_w (fp16)
    __half* xh    = (__half*)p;    p += NF * 2;      // normalized mean (fp16)
    char* tail = p;
    __half* z0h   = (__half*)p;    p += NF * 2;
    __half* z1h   = (__half*)p;    p += NF * 2;
    __half* t1h   = (__half*)p;    p += NF * 2;      // op1 result (fp16)
    int*    ptrA  = (int*)p;       p += (size_t)(N + 1) * 4;
    int*    ptrB  = (int*)p;       p += (size_t)(N + 1) * 4;
    int*    curA  = (int*)p;       p += (size_t)N * 4;
    int*    curB  = (int*)p;       p += (size_t)N * 4;
    int*    bsum  = (int*)p;       p += (size_t)nblk * 4;
    int*    bofs  = (int*)p;       p += (size_t)(nblk + 1) * 4;
    p = (char*)(((uintptr_t)p + 7) & ~(uintptr_t)7);
    unsigned long long* cpairA = (unsigned long long*)p; p += (size_t)MAXNNZ * 8;
    unsigned long long* cpairB = (unsigned long long*)p; p += (size_t)MAXNNZ * 8;
    const size_t need_csr = p - (char*)d_ws;
    const bool csr_ok = (ws_size >= need_csr);
    int* ptrS[2] = {ptrA, ptrB};
    int* curS[2] = {curA, curB};
    unsigned long long* cpairS[2] = {cpairA, cpairB};
    (void)n_in; (void)out_size;

    // --- degree / dinv (over edge cols, +1 self-loop); dinv zeroes cnt ---
    (void)hipMemsetAsync(cnt, 0, (size_t)N * sizeof(int), stream);
    hist_kernel<<<(E + 255) / 256, 256, 0, stream>>>(edge_index + E, cnt, E);
    dinv_kernel<<<(N + 255) / 256, 256, 0, stream>>>(cnt, dinv, N);

    // --- dual GEMM: mean0(prenorm,fp32) -> out1 ; xw(fp16) -> xwh ---
    gemm_fused<<<dim3((N + 63) / 64, 4), 256, 0, stream>>>(
        x, lin_w, lin_b, gw_w, out1, xwh, N);
    rownorm_kernel<<<(N + 3) / 4, 256, 0, stream>>>(out1, xh, N);

    if (csr_ok) {
        // op table: [APPNP, A0, B0, A1, B1, A2, B2]
        struct Op {
            const int* rows; const int* cols; const float* vals;
            int mode; int nnz;
            const __half* src; const float* init_src;
            float* dstf; __half* dsth;
        } ops[7];
        ops[0] = {edge_index, edge_index + E, nullptr, 2, E,
                  xh, out1, out0, nullptr};
        for (int i = 0; i < 3; ++i) {
            const int* ri1 = phi_inv_idx + (size_t)i * 2 * NNZ;
            const int* ri2 = phi_idx + (size_t)i * 2 * NNZ;
            ops[1 + 2 * i] = {ri1, ri1 + NNZ, phi_inv_vals + (size_t)i * NNZ,
                              0, NNZ, xwh, nullptr, nullptr, t1h};
            float*  bf = (i == 2) ? out1 : nullptr;
            __half* bh = (i == 0) ? z0h : (i == 1) ? z1h : nullptr;
            ops[2 + 2 * i] = {ri2, ri2 + NNZ, phi_vals + (size_t)i * NNZ,
                              1, NNZ, t1h, nullptr, bf, bh};
        }

        auto scans = [&](int k) {   // cnt -> ptr/cursor[k&1]; zeroes cnt
            scan_reduce_kernel<<<nblk, 256, 0, stream>>>(cnt, bsum, N);
            scan_bsum_kernel<<<1, 64, 0, stream>>>(bsum, bofs, ptrS[k & 1], nblk, N);
            scan_block_kernel<<<nblk, 256, 0, stream>>>(cnt, bofs, ptrS[k & 1],
                                                        curS[k & 1], N);
        };

        const int GRID = 2048;
        // prologue: hist0; scans0; [build0 || hist1] (mix=2: 12B/4H); scans1
        hist_kernel<<<(ops[0].nnz + 255) / 256, 256, 0, stream>>>(
            ops[0].rows, cnt, ops[0].nnz);
        scans(0);
        fused_pipe_kernel<<<GRID, 256, 0, stream>>>(
            nullptr, nullptr, nullptr, nullptr, dinv, nullptr, nullptr, N, 0,
            ops[0].rows, ops[0].cols, ops[0].vals, diag_w, curS[0], cpairS[0],
            ops[0].nnz, ops[0].mode,
            ops[1].rows, cnt, ops[1].nnz, 2);
        scans(1);

        // steady state: F_k = gather_k || build_{k+1} || hist_{k+2}
        for (int k = 0; k < 7; ++k) {
            const Op& g = ops[k];
            const bool hb = (k < 6), hh = (k < 5);
            const Op* b = hb ? &ops[k + 1] : nullptr;
            fused_pipe_kernel<<<GRID, 256, 0, stream>>>(
                ptrS[k & 1], (const int2*)cpairS[k & 1], g.src, g.init_src,
                dinv, g.dstf, g.dsth, N, g.nnz,
                hb ? b->rows : nullptr, hb ? b->cols : nullptr,
                hb ? b->vals : nullptr, diag_w,
                hb ? curS[(k + 1) & 1] : nullptr,
                hb ? cpairS[(k + 1) & 1] : nullptr,
                hb ? b->nnz : 0, hb ? b->mode : 0,
                hh ? ops[k + 2].rows : nullptr, cnt, hh ? ops[k + 2].nnz : 0,
                hb ? 1 : 0);
            if (hh) scans(k + 2);
        }

        // --- attention pooling, in place: out1 = pool(z0h, z1h, out1) ---
        attn_h_kernel<<<2048, 256, 0, stream>>>(z0h, z1h, out1, att_w1, att_b1,
                                                att_w2, out1, N);
    } else {
        // --------- fallback: atomic scatter path (fp32 z) ---------
        float*  z0f  = (float*)tail;
        float*  z1f  = z0f + NF;
        float*  t1f  = z1f + NF;
        __half* t1hf = (__half*)(t1f + NF);
        for (int i = 0; i < 3; ++i) {
            const int* ri1 = phi_inv_idx + (size_t)i * 2 * NNZ;
            const int* ci1 = ri1 + NNZ;
            const int* ri2 = phi_idx + (size_t)i * 2 * NNZ;
            const int* ci2 = ri2 + NNZ;
            float* zdst = (i == 0) ? z0f : (i == 1) ? z1f : out0;

            (void)hipMemsetAsync(t1f, 0, NF * sizeof(float), stream);
            spmm_h_kernel<<<(NNZ + 3) / 4, 256, 0, stream>>>(
                ri1, ci1, phi_inv_vals + (size_t)i * NNZ, nullptr, xwh, t1f, NNZ);
            f2h_kernel<<<((NF / 2) + 255) / 256, 256, 0, stream>>>(t1f, t1hf,
                                                                   NF / 2);
            (void)hipMemsetAsync(zdst, 0, NF * sizeof(float), stream);
            spmm_h_kernel<<<(NNZ + 3) / 4, 256, 0, stream>>>(
                ri2, ci2, phi_vals + (size_t)i * NNZ, diag_w, t1hf, zdst, NNZ);
        }
        attn_f_kernel<<<2048, 256, 0, stream>>>(z0f, z1f, out0, att_w1, att_b1,
                                                att_w2, t1f, N);
        appnp_init_kernel<<<((size_t)N * 32 + 255) / 256, 256, 0, stream>>>(
            out1, dinv, out0, N);
        appnp_edge_h_kernel<<<(E + 3) / 4, 256, 0, stream>>>(
            edge_index, edge_index + E, dinv, xh, out0, E);
        (void)hipMemcpyAsync(out1, t1f, NF * sizeof(float),
                             hipMemcpyDeviceToDevice, stream);
    }
}